// Round 1
// 517.587 us; speedup vs baseline: 1.0778x; 1.0778x over previous
//
#include <hip/hip_runtime.h>
#include <math.h>

#define T_TOK 16384
#define M_MSG 256
#define L_TOK 64
#define KK 6
#define NQ (M_MSG * KK)   // 1536
#define D_HID 256
#define NH 4
#define HD 64
#define KT 10
#define NBATCH 8

// ---------- helpers ----------
__device__ __forceinline__ unsigned ordf(float f) {
  unsigned u = __float_as_uint(f);
  return (u & 0x80000000u) ? ~u : (u | 0x80000000u);
}
__device__ __forceinline__ float unordf(unsigned u) {
  return __uint_as_float((u & 0x80000000u) ? (u ^ 0x80000000u) : ~u);
}

// ---------- 1. importance MLP: imp[t] = relu(X@Wi1^T + bi1) @ Wi2^T + bi2 ----------
__global__ __launch_bounds__(128) void imp_kernel(
    const float* __restrict__ X, const float* __restrict__ Wi1,
    const float* __restrict__ bi1, const float* __restrict__ Wi2,
    const float* __restrict__ bi2, float* __restrict__ imp) {
  __shared__ float xs[16][256];
  __shared__ float partial[2][16];
  int t0 = blockIdx.x * 16;
  int tid = threadIdx.x;  // 0..127, = hidden index j
  const float4* Xv = (const float4*)(X + (size_t)t0 * 256);
  float4* xsv = (float4*)&xs[0][0];
  for (int r = tid; r < 1024; r += 128) xsv[r] = Xv[r];
  __syncthreads();
  float acc[16];
#pragma unroll
  for (int tt = 0; tt < 16; ++tt) acc[tt] = 0.f;
  const float4* Wrow = (const float4*)(Wi1 + tid * 256);
  for (int i4 = 0; i4 < 64; ++i4) {
    float4 w = Wrow[i4];
#pragma unroll
    for (int tt = 0; tt < 16; ++tt) {
      float4 x = ((const float4*)xs[tt])[i4];
      acc[tt] += x.x * w.x + x.y * w.y + x.z * w.z + x.w * w.w;
    }
  }
  float b1 = bi1[tid], w2 = Wi2[tid];
  float p[16];
#pragma unroll
  for (int tt = 0; tt < 16; ++tt) {
    float hh = acc[tt] + b1;
    hh = hh > 0.f ? hh : 0.f;
    p[tt] = hh * w2;
  }
#pragma unroll
  for (int s = 1; s < 64; s <<= 1) {
#pragma unroll
    for (int tt = 0; tt < 16; ++tt) p[tt] += __shfl_xor(p[tt], s, 64);
  }
  int lane = tid & 63, w = tid >> 6;
  if (lane == 0) {
#pragma unroll
    for (int tt = 0; tt < 16; ++tt) partial[w][tt] = p[tt];
  }
  __syncthreads();
  if (tid < 16) imp[t0 + tid] = partial[0][tid] + partial[1][tid] + bi2[0];
}

// ---------- 2. per-message top-6 (desc value, tie -> lower index) ----------
__global__ __launch_bounds__(64) void topsel_kernel(
    const float* __restrict__ imp, const int* __restrict__ mb,
    int* __restrict__ selected) {
  int m = blockIdx.x;
  int l = threadIdx.x;  // 0..63
  float myv = imp[m * 64 + l];
  int start = mb[2 * m];
  for (int k = 0; k < KK; ++k) {
    float rv = myv;
    int ri = l;
#pragma unroll
    for (int s = 1; s < 64; s <<= 1) {
      float ov = __shfl_xor(rv, s, 64);
      int oi = __shfl_xor(ri, s, 64);
      if (ov > rv || (ov == rv && oi < ri)) { rv = ov; ri = oi; }
    }
    if (l == 0) selected[m * KK + k] = start + ri;
    if (l == ri) myv = -INFINITY;
  }
}

// ---------- 3. batch token ranges ----------
__global__ void ranges_kernel(const int* __restrict__ bidx,
                              int* __restrict__ lo, int* __restrict__ hi) {
  int g = threadIdx.x;  // 0..7
  if (g >= NBATCH) return;
  int l = 0;
  while (l < M_MSG && bidx[l] < g) ++l;
  int h = l;
  while (h < M_MSG && bidx[h] == g) ++h;
  lo[g] = l * L_TOK;
  hi[g] = h * L_TOK;
}

// ---------- 4. generic projection ----------
// hm=0: out[r][j] = (dot(X[row r], W[j]) + b[j]) * scale  (row-major [R][256])
// hm=1: head/half-major K layout K3[h][p][t][32] with j = h*64 + p*32 + dd,
//       so that a (batch,head) key slab is CONTIGUOUS for coalesced staging.
__global__ __launch_bounds__(256) void proj_kernel(
    const float* __restrict__ X, const float* __restrict__ W,
    const float* __restrict__ b, float* __restrict__ out,
    const int* __restrict__ rows, int R, float scale, int hm) {
  __shared__ float xs[32][256];
  int r0 = blockIdx.x * 32;
  int tid = threadIdx.x;  // output column j
  for (int rr = 0; rr < 32; ++rr) {
    int r = r0 + rr;
    if (r < R) {
      int src = rows ? rows[r] : r;
      xs[rr][tid] = X[(size_t)src * 256 + tid];
    }
  }
  __syncthreads();
  float acc[32];
#pragma unroll
  for (int tt = 0; tt < 32; ++tt) acc[tt] = 0.f;
  const float4* Wrow = (const float4*)(W + tid * 256);
  for (int i4 = 0; i4 < 64; ++i4) {
    float4 w = Wrow[i4];
#pragma unroll
    for (int tt = 0; tt < 32; ++tt) {
      float4 x = ((const float4*)xs[tt])[i4];
      acc[tt] += x.x * w.x + x.y * w.y + x.z * w.z + x.w * w.w;
    }
  }
  float bj = b[tid];
#pragma unroll 1
  for (int tt = 0; tt < 32; ++tt) {
    int r = r0 + tt;
    if (r < R) {
      float v = (acc[tt] + bj) * scale;
      if (hm) {
        size_t oi = (((size_t)(tid >> 6) * 2 + ((tid >> 5) & 1)) * T_TOK + r) * 32 +
                    (tid & 31);
        out[oi] = v;
      } else {
        out[(size_t)r * 256 + tid] = v;
      }
    }
  }
}

// ---------- 5. scores + top-10 per (query, head) ----------
// block = swizzled (message m, head h); 128 threads = 2 waves.
// K is in head/half-major layout K3[h][p][T][32]; keys are processed in
// 128-key tiles, each tile = 2 stages (dim halves) of 16 KB staged
// global->reg (fully coalesced) ->LDS (XOR slot swizzle, bank-floor reads),
// double-buffered so the next stage's HBM/L2 latency hides under FMAs.
// Wave w owns queries w*3+{0,1,2}; thread lane L computes keys {L, L+64} of
// the tile for those 3 queries, so selection runs straight out of registers
// (no score round-trip through LDS).
__global__ __launch_bounds__(128) void scores_kernel(
    const float* __restrict__ Q, const float* __restrict__ K3,
    const int* __restrict__ lo_, const int* __restrict__ hi_,
    const int* __restrict__ bidx,
    float* __restrict__ topv, int* __restrict__ topi) {
  int b = blockIdx.x;
  // XCD swizzle: 1024 blocks, 8 XCDs -> each XCD gets a contiguous 128-block
  // slab = ~one batch (bidx sorted) so its K slice stays in that XCD's L2.
  int sw = (b & 7) * (M_MSG * NH / 8) + (b >> 3);
  int m = sw >> 2, h = sw & 3;
  int tid = threadIdx.x, lane = tid & 63, w = tid >> 6;
  int g = bidx[m];
  int lo = lo_[g], hi = hi_[g];

  __shared__ float4 qs4[KK][16];     // 6 queries x 64 dims
  __shared__ float4 kt4[2][1024];    // 2 x (128 keys x 32 dims), slot-swizzled

  const float4* Qv = (const float4*)Q;
  const float4* Kv = (const float4*)K3;

  float4 pre[8];
  int range = hi - lo;
  int ntiles = (range + 127) >> 7;
  int S = ntiles * 2;

  // coalesced stage prefetch: unit n covers key k=n>>3, phys slot sp=n&7;
  // store logical slot s = sp ^ (k&7) there (inverse-swizzled source).
  auto stage_load = [&](int st2) {
    int kb2 = st2 >> 1, p2 = st2 & 1;
    const float4* Kh = Kv + (size_t)(h * 2 + p2) * T_TOK * 8;
#pragma unroll
    for (int u = 0; u < 8; ++u) {
      int n = u * 128 + tid;
      int k = n >> 3;
      int s = (n & 7) ^ (k & 7);
      int kg = lo + kb2 * 128 + k;
      if (kg >= hi) kg = hi - 1;
      pre[u] = Kh[(size_t)kg * 8 + s];
    }
  };

  stage_load(0);

  for (int i = tid; i < KK * 16; i += 128) {
    int qq = i >> 4, d4 = i & 15;
    qs4[qq][d4] = Qv[(size_t)(m * KK + qq) * 64 + h * 16 + d4];
  }

  unsigned long long lst[3][KT];
#pragma unroll
  for (int j = 0; j < 3; ++j)
#pragma unroll
    for (int k = 0; k < KT; ++k) lst[j][k] = 0ULL;

  float acc[3][2];
  int L = lane;
  int base0 = L * 8, base1 = (L + 64) * 8;
  int sw7 = L & 7;

  for (int st = 0; st < S; ++st) {
    int kb = st >> 1, p = st & 1;
    __syncthreads();  // kt[st&1] free (read 2 stages ago), qs visible
    {
      float4* dst = kt4[st & 1];
#pragma unroll
      for (int u = 0; u < 8; ++u) dst[u * 128 + tid] = pre[u];
    }
    if (st + 1 < S) stage_load(st + 1);
    __syncthreads();  // tile half visible to both waves

    if (p == 0) {
#pragma unroll
      for (int j = 0; j < 3; ++j) { acc[j][0] = 0.f; acc[j][1] = 0.f; }
    }
    const float4* kt = kt4[st & 1];
#pragma unroll
    for (int s = 0; s < 8; ++s) {
      float4 k0 = kt[base0 + (s ^ sw7)];
      float4 k1 = kt[base1 + (s ^ sw7)];
#pragma unroll
      for (int j = 0; j < 3; ++j) {
        float4 q = qs4[w * 3 + j][p * 8 + s];
        acc[j][0] += k0.x * q.x + k0.y * q.y + k0.z * q.z + k0.w * q.w;
        acc[j][1] += k1.x * q.x + k1.y * q.y + k1.z * q.z + k1.w * q.w;
      }
    }

    if (p == 1) {
      // register-resident top-k update for this 128-key tile
      int key0 = lo + kb * 128 + L;
      bool v0 = (key0 < hi) && ((key0 >> 6) != m);
      bool v1 = (key0 + 64 < hi) && (((key0 + 64) >> 6) != m);
#pragma unroll
      for (int j = 0; j < 3; ++j) {
        unsigned cc0 = v0 ? ordf(acc[j][0]) : 0u;
        unsigned cc1 = v1 ? ordf(acc[j][1]) : 0u;
        bool done = false;
#pragma unroll
        for (int k = 0; k < KT; ++k) {
          if (!done) {
            unsigned bv = cc0;
            int bt = key0;
            if (cc1 > cc0) { bv = cc1; bt = key0 + 64; }
            // cross-lane argmax, tie -> lower token idx
#pragma unroll
            for (int s_ = 1; s_ < 64; s_ <<= 1) {
              unsigned ov = (unsigned)__shfl_xor((int)bv, s_, 64);
              int ot = __shfl_xor(bt, s_, 64);
              if (ov > bv || (ov == bv && ot < bt)) { bv = ov; bt = ot; }
            }
            unsigned long long kkey =
                bv ? (((unsigned long long)bv << 32) | (unsigned)(~bt)) : 0ULL;
            if (kkey <= lst[j][KT - 1]) {
              done = true;  // uniform: nothing left can enter the list
            } else {
              int rel = bt - (lo + kb * 128);
              if ((rel & 63) == L) {
                if (rel >> 6) cc1 = 0u; else cc0 = 0u;
              }
              // bubble-insert into sorted-desc running list
              unsigned long long ins = kkey;
#pragma unroll
              for (int r = 0; r < KT; ++r) {
                unsigned long long cur = lst[j][r];
                unsigned long long mx = ins > cur ? ins : cur;
                unsigned long long mn = ins > cur ? cur : ins;
                lst[j][r] = mx;
                ins = mn;
              }
            }
          }
        }
      }
    }
  }

  // ---- output: lane 0 of each wave writes its 3 queries ----
  if (lane == 0) {
#pragma unroll
    for (int j = 0; j < 3; ++j) {
      int q = m * KK + w * 3 + j;
#pragma unroll
      for (int k = 0; k < KT; ++k) {
        unsigned long long v = lst[j][k];
        float scv;
        int t;
        if (v != 0ULL) {
          scv = unordf((unsigned)(v >> 32));
          t = (int)(~(unsigned)v);
        } else {
          scv = -1e30f;
          t = 0;
        }
        topv[(size_t)(q * NH + h) * KT + k] = scv;
        topi[(size_t)(q * NH + h) * KT + k] = t;
      }
    }
  }
}

// ---------- 6. softmax + gather V + Wo matvec + scatter-add + avg_scores ----------
__global__ __launch_bounds__(256) void finish_kernel(
    const float* __restrict__ topv, const int* __restrict__ topi,
    const float* __restrict__ V, const float* __restrict__ Wo,
    const float* __restrict__ bo, const int* __restrict__ selected,
    float* __restrict__ out, float* __restrict__ out_avg) {
  int q0 = blockIdx.x * 16;
  int tid = threadIdx.x;
  __shared__ float wsm[16][NH * KT];
  __shared__ float att[16][256];
  if (tid < 64) {
    int qq = tid >> 2, h = tid & 3;
    int q = q0 + qq;
    const float* tv = topv + (size_t)(q * NH + h) * KT;
    float mx = tv[0];
    float e[KT];
    float sum = 0.f;
#pragma unroll
    for (int k = 0; k < KT; ++k) { e[k] = expf(tv[k] - mx); sum += e[k]; }
    float inv = 1.f / sum;
#pragma unroll
    for (int k = 0; k < KT; ++k) wsm[qq][h * KT + k] = e[k] * inv;
  } else if (tid < 64 + 160) {
    int i = tid - 64;
    int qq = i / 10, k = i % 10;
    int q = q0 + qq;
    out_avg[(size_t)q * KT + k] =
        0.25f * (topv[(size_t)(q * NH + 0) * KT + k] +
                 topv[(size_t)(q * NH + 1) * KT + k] +
                 topv[(size_t)(q * NH + 2) * KT + k] +
                 topv[(size_t)(q * NH + 3) * KT + k]);
  }
  __syncthreads();
  int h = tid >> 6, d = tid & 63;
#pragma unroll 1
  for (int qq = 0; qq < 16; ++qq) {
    int q = q0 + qq;
    float a = 0.f;
#pragma unroll
    for (int k = 0; k < KT; ++k) {
      int t = topi[(size_t)(q * NH + h) * KT + k];
      a += wsm[qq][h * KT + k] * V[(size_t)t * 256 + h * 64 + d];
    }
    att[qq][tid] = a;
  }
  __syncthreads();
  float acc[16];
#pragma unroll
  for (int tt = 0; tt < 16; ++tt) acc[tt] = 0.f;
  const float4* Wrow = (const float4*)(Wo + tid * 256);
  for (int i4 = 0; i4 < 64; ++i4) {
    float4 wv = Wrow[i4];
#pragma unroll
    for (int tt = 0; tt < 16; ++tt) {
      float4 x = ((const float4*)att[tt])[i4];
      acc[tt] += x.x * wv.x + x.y * wv.y + x.z * wv.z + x.w * wv.w;
    }
  }
  float bj = bo[tid];
#pragma unroll 1
  for (int tt = 0; tt < 16; ++tt) {
    int s = selected[q0 + tt];
    out[(size_t)s * 256 + tid] += acc[tt] + bj;
  }
}

// ---------- launch ----------
extern "C" void kernel_launch(void* const* d_in, const int* in_sizes, int n_in,
                              void* d_out, int out_size, void* d_ws, size_t ws_size,
                              hipStream_t stream) {
  const float* X   = (const float*)d_in[0];
  const int*   mb  = (const int*)d_in[1];
  const int*   bidx= (const int*)d_in[2];
  const float* Wq  = (const float*)d_in[3];
  const float* bq  = (const float*)d_in[4];
  const float* Wk  = (const float*)d_in[5];
  const float* bk  = (const float*)d_in[6];
  const float* Wv  = (const float*)d_in[7];
  const float* bv  = (const float*)d_in[8];
  const float* Wi1 = (const float*)d_in[9];
  const float* bi1 = (const float*)d_in[10];
  const float* Wi2 = (const float*)d_in[11];
  const float* bi2 = (const float*)d_in[12];
  const float* Wo  = (const float*)d_in[13];
  const float* bo  = (const float*)d_in[14];

  float* out = (float*)d_out;
  float* out_avg = out + (size_t)T_TOK * D_HID;

  // K is staged in d_out's "updated" region (dead until final memcpy+scatter).
  float* Kmat = out;

  char* ws = (char*)d_ws;
  size_t off = 0;
  float* V = (float*)(ws + off);        off += (size_t)T_TOK * 256 * 4;   // 16.78 MB
  float* Q = (float*)(ws + off);        off += (size_t)NQ * 256 * 4;      // 1.57 MB
  float* imp = (float*)(ws + off);      off += (size_t)T_TOK * 4;
  int* selected = (int*)(ws + off);     off += (size_t)NQ * 4;
  int* lo = (int*)(ws + off);           off += 64;
  int* hi = (int*)(ws + off);           off += 64;
  float* topv = (float*)(ws + off);     off += (size_t)NQ * NH * KT * 4;
  int* topi = (int*)(ws + off);         off += (size_t)NQ * NH * KT * 4;
  (void)ws_size; (void)in_sizes; (void)n_in; (void)out_size;

  imp_kernel<<<T_TOK / 16, 128, 0, stream>>>(X, Wi1, bi1, Wi2, bi2, imp);
  topsel_kernel<<<M_MSG, 64, 0, stream>>>(imp, mb, selected);
  ranges_kernel<<<1, 8, 0, stream>>>(bidx, lo, hi);
  proj_kernel<<<T_TOK / 32, 256, 0, stream>>>(X, Wk, bk, Kmat, nullptr, T_TOK, 1.0f, 1);
  proj_kernel<<<T_TOK / 32, 256, 0, stream>>>(X, Wv, bv, V, nullptr, T_TOK, 1.0f, 0);
  proj_kernel<<<NQ / 32, 256, 0, stream>>>(X, Wq, bq, Q, selected, NQ, 0.125f, 0);
  scores_kernel<<<M_MSG * NH, 128, 0, stream>>>(Q, Kmat, lo, hi, bidx, topv, topi);
  hipMemcpyAsync(out, X, (size_t)T_TOK * D_HID * sizeof(float),
                 hipMemcpyDeviceToDevice, stream);
  finish_kernel<<<NQ / 16, 256, 0, stream>>>(topv, topi, V, Wo, bo, selected,
                                             out, out_avg);
}

// Round 2
// 452.318 us; speedup vs baseline: 1.2333x; 1.1443x over previous
//
#include <hip/hip_runtime.h>
#include <math.h>

#define T_TOK 16384
#define M_MSG 256
#define L_TOK 64
#define KK 6
#define NQ (M_MSG * KK)   // 1536
#define D_HID 256
#define NH 4
#define HD 64
#define KT 10
#define NBATCH 8

// raw barrier: ds-write visibility only (lgkmcnt), vmcnt prefetch stays in flight
#define BAR() do {                                        \
    asm volatile("s_waitcnt lgkmcnt(0)" ::: "memory");    \
    __builtin_amdgcn_s_barrier();                         \
    asm volatile("" ::: "memory");                        \
  } while (0)

// ---------- helpers ----------
__device__ __forceinline__ unsigned ordf(float f) {
  unsigned u = __float_as_uint(f);
  return (u & 0x80000000u) ? ~u : (u | 0x80000000u);
}
__device__ __forceinline__ float unordf(unsigned u) {
  return __uint_as_float((u & 0x80000000u) ? (u ^ 0x80000000u) : ~u);
}

// ---------- 1. importance MLP ----------
__global__ __launch_bounds__(128) void imp_kernel(
    const float* __restrict__ X, const float* __restrict__ Wi1,
    const float* __restrict__ bi1, const float* __restrict__ Wi2,
    const float* __restrict__ bi2, float* __restrict__ imp) {
  __shared__ float xs[16][256];
  __shared__ float partial[2][16];
  int t0 = blockIdx.x * 16;
  int tid = threadIdx.x;  // 0..127, = hidden index j
  const float4* Xv = (const float4*)(X + (size_t)t0 * 256);
  float4* xsv = (float4*)&xs[0][0];
  for (int r = tid; r < 1024; r += 128) xsv[r] = Xv[r];
  __syncthreads();
  float acc[16];
#pragma unroll
  for (int tt = 0; tt < 16; ++tt) acc[tt] = 0.f;
  const float4* Wrow = (const float4*)(Wi1 + tid * 256);
  for (int i4 = 0; i4 < 64; ++i4) {
    float4 w = Wrow[i4];
#pragma unroll
    for (int tt = 0; tt < 16; ++tt) {
      float4 x = ((const float4*)xs[tt])[i4];
      acc[tt] += x.x * w.x + x.y * w.y + x.z * w.z + x.w * w.w;
    }
  }
  float b1 = bi1[tid], w2 = Wi2[tid];
  float p[16];
#pragma unroll
  for (int tt = 0; tt < 16; ++tt) {
    float hh = acc[tt] + b1;
    hh = hh > 0.f ? hh : 0.f;
    p[tt] = hh * w2;
  }
#pragma unroll
  for (int s = 1; s < 64; s <<= 1) {
#pragma unroll
    for (int tt = 0; tt < 16; ++tt) p[tt] += __shfl_xor(p[tt], s, 64);
  }
  int lane = tid & 63, w = tid >> 6;
  if (lane == 0) {
#pragma unroll
    for (int tt = 0; tt < 16; ++tt) partial[w][tt] = p[tt];
  }
  __syncthreads();
  if (tid < 16) imp[t0 + tid] = partial[0][tid] + partial[1][tid] + bi2[0];
}

// ---------- 2. per-message top-6 (desc value, tie -> lower index) ----------
__global__ __launch_bounds__(64) void topsel_kernel(
    const float* __restrict__ imp, const int* __restrict__ mb,
    int* __restrict__ selected) {
  int m = blockIdx.x;
  int l = threadIdx.x;  // 0..63
  float myv = imp[m * 64 + l];
  int start = mb[2 * m];
  for (int k = 0; k < KK; ++k) {
    float rv = myv;
    int ri = l;
#pragma unroll
    for (int s = 1; s < 64; s <<= 1) {
      float ov = __shfl_xor(rv, s, 64);
      int oi = __shfl_xor(ri, s, 64);
      if (ov > rv || (ov == rv && oi < ri)) { rv = ov; ri = oi; }
    }
    if (l == 0) selected[m * KK + k] = start + ri;
    if (l == ri) myv = -INFINITY;
  }
}

// ---------- 3. batch token ranges ----------
__global__ void ranges_kernel(const int* __restrict__ bidx,
                              int* __restrict__ lo, int* __restrict__ hi) {
  int g = threadIdx.x;  // 0..7
  if (g >= NBATCH) return;
  int l = 0;
  while (l < M_MSG && bidx[l] < g) ++l;
  int h = l;
  while (h < M_MSG && bidx[h] == g) ++h;
  lo[g] = l * L_TOK;
  hi[g] = h * L_TOK;
}

// ---------- 4a. fused K+V projection ----------
// K goes to head/half-major layout K3[h][p][t][32]; V stays row-major.
__global__ __launch_bounds__(256) void projkv_kernel(
    const float* __restrict__ X, const float* __restrict__ Wk,
    const float* __restrict__ bk, const float* __restrict__ Wv,
    const float* __restrict__ bv, float* __restrict__ Kout,
    float* __restrict__ Vout) {
  __shared__ float xs[16][256];
  int r0 = blockIdx.x * 16;
  int tid = threadIdx.x;  // output column j
  const float4* Xv = (const float4*)(X + (size_t)r0 * 256);
  float4* xsv = (float4*)&xs[0][0];
  for (int n = tid; n < 1024; n += 256) xsv[n] = Xv[n];
  __syncthreads();
  float ak[16], av[16];
#pragma unroll
  for (int tt = 0; tt < 16; ++tt) { ak[tt] = 0.f; av[tt] = 0.f; }
  const float4* Wkr = (const float4*)(Wk + tid * 256);
  const float4* Wvr = (const float4*)(Wv + tid * 256);
  for (int i4 = 0; i4 < 64; ++i4) {
    float4 wk = Wkr[i4];
    float4 wv = Wvr[i4];
#pragma unroll
    for (int tt = 0; tt < 16; ++tt) {
      float4 x = ((const float4*)xs[tt])[i4];
      ak[tt] += x.x * wk.x + x.y * wk.y + x.z * wk.z + x.w * wk.w;
      av[tt] += x.x * wv.x + x.y * wv.y + x.z * wv.z + x.w * wv.w;
    }
  }
  float bkj = bk[tid], bvj = bv[tid];
  size_t kb = (size_t)((tid >> 6) * 2 + ((tid >> 5) & 1));
#pragma unroll 1
  for (int tt = 0; tt < 16; ++tt) {
    int r = r0 + tt;
    Kout[(kb * T_TOK + r) * 32 + (tid & 31)] = ak[tt] + bkj;
    Vout[(size_t)r * 256 + tid] = av[tt] + bvj;
  }
}

// ---------- 4b. Q projection (row-major out, gathered rows, scaled) ----------
__global__ __launch_bounds__(256) void proj_kernel(
    const float* __restrict__ X, const float* __restrict__ W,
    const float* __restrict__ b, float* __restrict__ out,
    const int* __restrict__ rows, int R, float scale) {
  __shared__ float xs[32][256];
  int r0 = blockIdx.x * 32;
  int tid = threadIdx.x;  // output column j
  for (int rr = 0; rr < 32; ++rr) {
    int r = r0 + rr;
    if (r < R) {
      int src = rows ? rows[r] : r;
      xs[rr][tid] = X[(size_t)src * 256 + tid];
    }
  }
  __syncthreads();
  float acc[32];
#pragma unroll
  for (int tt = 0; tt < 32; ++tt) acc[tt] = 0.f;
  const float4* Wrow = (const float4*)(W + tid * 256);
  for (int i4 = 0; i4 < 64; ++i4) {
    float4 w = Wrow[i4];
#pragma unroll
    for (int tt = 0; tt < 32; ++tt) {
      float4 x = ((const float4*)xs[tt])[i4];
      acc[tt] += x.x * w.x + x.y * w.y + x.z * w.z + x.w * w.w;
    }
  }
  float bj = b[tid];
#pragma unroll 1
  for (int tt = 0; tt < 32; ++tt) {
    int r = r0 + tt;
    if (r < R) out[(size_t)r * 256 + tid] = (acc[tt] + bj) * scale;
  }
}

// ---------- 5. scores + per-split top-10 ----------
// block = (m, h, split): 2048 blocks, 128 threads (2 waves).
// K tiles 64 keys x 32 dims (8 KB), double-buffered (LDS 17.9 KB -> 8 blk/CU,
// 4 waves/SIMD resident). Raw s_barrier (lgkmcnt only) keeps the global
// prefetch in flight across barriers; vmcnt drains one full compute phase
// after issue. Lane L owns key L of each tile; top-10 kept as per-lane
// register lists of u64 (ord(score)<<32 | ~token) -> zero cross-lane ops in
// the hot loop; one shfl extraction-merge at the end writes sorted u64 lists.
__global__ __launch_bounds__(128) void scores_kernel(
    const float* __restrict__ Q, const float* __restrict__ K3,
    const int* __restrict__ lo_, const int* __restrict__ hi_,
    const int* __restrict__ bidx, unsigned long long* __restrict__ topk2) {
  int bid = blockIdx.x;
  int sp = bid & 1;
  int h = (bid >> 1) & 3;
  int m = bid >> 3;
  int tid = threadIdx.x, lane = tid & 63, w = tid >> 6;
  int g = bidx[m];
  int lo = lo_[g], hi = hi_[g];
  int range = hi - lo;
  int n_all = (range + 63) >> 6;
  int n0 = (n_all + 1) >> 1;
  int nt = sp ? (n_all - n0) : n0;
  int start = lo + (sp ? n0 * 64 : 0);
  int end0 = lo + n0 * 64;
  int end = sp ? hi : (end0 < hi ? end0 : hi);

  __shared__ float4 qs4[KK][16];   // 6 queries x 64 dims (1.5 KB)
  __shared__ float4 kt4[2][512];   // 2 x (64 keys x 32 dims) (16 KB)

  const float4* Qv = (const float4*)Q;
  const float4* Kv = (const float4*)K3;

  float4 pre[4];
  int S = nt * 2;

  auto stage_load = [&](int st2) {
    int kb2 = st2 >> 1, p2 = st2 & 1;
    const float4* Kh = Kv + (size_t)(h * 2 + p2) * T_TOK * 8;
#pragma unroll
    for (int u = 0; u < 4; ++u) {
      int n = u * 128 + tid;
      int k = n >> 3;
      int s = (n & 7) ^ (k & 7);
      int kg = start + kb2 * 64 + k;
      if (kg >= hi) kg = hi - 1;
      pre[u] = Kh[(size_t)kg * 8 + s];
    }
  };

  if (S > 0) stage_load(0);

  for (int i = tid; i < KK * 16; i += 128) {
    int qq = i >> 4, d4 = i & 15;
    qs4[qq][d4] = Qv[(size_t)(m * KK + qq) * 64 + h * 16 + d4];
  }

  unsigned long long lst[3][KT];
#pragma unroll
  for (int j = 0; j < 3; ++j)
#pragma unroll
    for (int k = 0; k < KT; ++k) lst[j][k] = 0ULL;

  float acc[3];
  int L = lane;
  int base0 = L * 8;
  int sw7 = L & 7;

  for (int st = 0; st < S; ++st) {
    int kb = st >> 1, p = st & 1;
    BAR();  // kt4[st&1] free (consumed 2 stages ago); qs4/prev writes visible
    {
      float4* dst = kt4[st & 1];
#pragma unroll
      for (int u = 0; u < 4; ++u) dst[u * 128 + tid] = pre[u];
    }
    if (st + 1 < S) stage_load(st + 1);
    BAR();  // tile visible to both waves; prefetch stays in flight (vmcnt)

    if (p == 0) { acc[0] = 0.f; acc[1] = 0.f; acc[2] = 0.f; }
    const float4* kt = kt4[st & 1];
#pragma unroll
    for (int s = 0; s < 8; ++s) {
      float4 k0 = kt[base0 + (s ^ sw7)];
#pragma unroll
      for (int j = 0; j < 3; ++j) {
        float4 q = qs4[w * 3 + j][p * 8 + s];
        acc[j] += k0.x * q.x + k0.y * q.y + k0.z * q.z + k0.w * q.w;
      }
    }

    if (p == 1) {
      int key0 = start + kb * 64 + L;
      bool v0 = (key0 < end) && ((key0 >> 6) != m);
      unsigned nk = ~(unsigned)key0;
#pragma unroll
      for (int j = 0; j < 3; ++j) {
        unsigned cc = v0 ? ordf(acc[j]) : 0u;
        unsigned long long key =
            cc ? (((unsigned long long)cc << 32) | nk) : 0ULL;
        if (key > lst[j][KT - 1]) {
          unsigned long long ins = key;
#pragma unroll
          for (int r = 0; r < KT; ++r) {
            unsigned long long cur = lst[j][r];
            unsigned long long mx = ins > cur ? ins : cur;
            unsigned long long mn = ins > cur ? cur : ins;
            lst[j][r] = mx;
            ins = mn;
          }
        }
      }
    }
  }

  // ---- extraction merge across 64 lanes (3 queries interleaved for ILP) ----
  for (int k = 0; k < KT; ++k) {
    unsigned long long mx[3];
#pragma unroll
    for (int j = 0; j < 3; ++j) mx[j] = lst[j][0];
#pragma unroll
    for (int s_ = 1; s_ < 64; s_ <<= 1) {
#pragma unroll
      for (int j = 0; j < 3; ++j) {
        unsigned long long o = __shfl_xor(mx[j], s_, 64);
        if (o > mx[j]) mx[j] = o;
      }
    }
#pragma unroll
    for (int j = 0; j < 3; ++j) {
      if (mx[j] != 0ULL && lst[j][0] == mx[j]) {
#pragma unroll
        for (int r = 0; r < KT - 1; ++r) lst[j][r] = lst[j][r + 1];
        lst[j][KT - 1] = 0ULL;
      }
    }
    if (lane == 0) {
#pragma unroll
      for (int j = 0; j < 3; ++j) {
        int q = m * KK + w * 3 + j;
        topk2[((size_t)(q * NH + h) * 2 + sp) * KT + k] = mx[j];
      }
    }
  }
}

// ---------- 5b. merge the two split lists (exact, sorted) ----------
__global__ __launch_bounds__(256) void merge_kernel(
    const unsigned long long* __restrict__ topk2, float* __restrict__ topv,
    int* __restrict__ topi) {
  __shared__ unsigned long long buf[256][2 * KT];  // 40 KB
  int tid = threadIdx.x;
  int i = blockIdx.x * 256 + tid;  // (q*NH+h)
  const unsigned long long* a = topk2 + (size_t)i * 2 * KT;
#pragma unroll
  for (int k = 0; k < 2 * KT; ++k) buf[tid][k] = a[k];
  int pa = 0, pb = 0;
  float* tv = topv + (size_t)i * KT;
  int* ti = topi + (size_t)i * KT;
  for (int k = 0; k < KT; ++k) {
    unsigned long long va = buf[tid][pa];
    unsigned long long vb = buf[tid][KT + pb];
    unsigned long long v;
    if (va >= vb) { v = va; ++pa; } else { v = vb; ++pb; }
    if (v != 0ULL) {
      tv[k] = unordf((unsigned)(v >> 32));
      ti[k] = (int)(~(unsigned)v);
    } else {
      tv[k] = -1e30f;
      ti[k] = 0;
    }
  }
}

// ---------- 6. softmax + gather V + Wo matvec + scatter-add + avg_scores ----------
__global__ __launch_bounds__(256) void finish_kernel(
    const float* __restrict__ topv, const int* __restrict__ topi,
    const float* __restrict__ V, const float* __restrict__ Wo,
    const float* __restrict__ bo, const int* __restrict__ selected,
    float* __restrict__ out, float* __restrict__ out_avg) {
  int q0 = blockIdx.x * 16;
  int tid = threadIdx.x;
  __shared__ float wsm[16][NH * KT];
  __shared__ float att[16][256];
  if (tid < 64) {
    int qq = tid >> 2, h = tid & 3;
    int q = q0 + qq;
    const float* tv = topv + (size_t)(q * NH + h) * KT;
    float mx = tv[0];
    float e[KT];
    float sum = 0.f;
#pragma unroll
    for (int k = 0; k < KT; ++k) { e[k] = expf(tv[k] - mx); sum += e[k]; }
    float inv = 1.f / sum;
#pragma unroll
    for (int k = 0; k < KT; ++k) wsm[qq][h * KT + k] = e[k] * inv;
  } else if (tid < 64 + 160) {
    int i = tid - 64;
    int qq = i / 10, k = i % 10;
    int q = q0 + qq;
    out_avg[(size_t)q * KT + k] =
        0.25f * (topv[(size_t)(q * NH + 0) * KT + k] +
                 topv[(size_t)(q * NH + 1) * KT + k] +
                 topv[(size_t)(q * NH + 2) * KT + k] +
                 topv[(size_t)(q * NH + 3) * KT + k]);
  }
  __syncthreads();
  int h = tid >> 6, d = tid & 63;
#pragma unroll 1
  for (int qq = 0; qq < 16; ++qq) {
    int q = q0 + qq;
    float a = 0.f;
#pragma unroll
    for (int k = 0; k < KT; ++k) {
      int t = topi[(size_t)(q * NH + h) * KT + k];
      a += wsm[qq][h * KT + k] * V[(size_t)t * 256 + h * 64 + d];
    }
    att[qq][tid] = a;
  }
  __syncthreads();
  float acc[16];
#pragma unroll
  for (int tt = 0; tt < 16; ++tt) acc[tt] = 0.f;
  const float4* Wrow = (const float4*)(Wo + tid * 256);
  for (int i4 = 0; i4 < 64; ++i4) {
    float4 wv = Wrow[i4];
#pragma unroll
    for (int tt = 0; tt < 16; ++tt) {
      float4 x = ((const float4*)att[tt])[i4];
      acc[tt] += x.x * wv.x + x.y * wv.y + x.z * wv.z + x.w * wv.w;
    }
  }
  float bj = bo[tid];
#pragma unroll 1
  for (int tt = 0; tt < 16; ++tt) {
    int s = selected[q0 + tt];
    out[(size_t)s * 256 + tid] += acc[tt] + bj;
  }
}

// ---------- launch ----------
extern "C" void kernel_launch(void* const* d_in, const int* in_sizes, int n_in,
                              void* d_out, int out_size, void* d_ws, size_t ws_size,
                              hipStream_t stream) {
  const float* X   = (const float*)d_in[0];
  const int*   mb  = (const int*)d_in[1];
  const int*   bidx= (const int*)d_in[2];
  const float* Wq  = (const float*)d_in[3];
  const float* bq  = (const float*)d_in[4];
  const float* Wk  = (const float*)d_in[5];
  const float* bk  = (const float*)d_in[6];
  const float* Wv  = (const float*)d_in[7];
  const float* bv  = (const float*)d_in[8];
  const float* Wi1 = (const float*)d_in[9];
  const float* bi1 = (const float*)d_in[10];
  const float* Wi2 = (const float*)d_in[11];
  const float* bi2 = (const float*)d_in[12];
  const float* Wo  = (const float*)d_in[13];
  const float* bo  = (const float*)d_in[14];

  float* out = (float*)d_out;
  float* out_avg = out + (size_t)T_TOK * D_HID;

  // K is staged in d_out's "updated" region (dead until final memcpy+scatter).
  float* Kmat = out;

  char* ws = (char*)d_ws;
  size_t off = 0;
  float* V = (float*)(ws + off);        off += (size_t)T_TOK * 256 * 4;   // 16.78 MB
  float* Q = (float*)(ws + off);        off += (size_t)NQ * 256 * 4;      // 1.57 MB
  float* imp = (float*)(ws + off);      off += (size_t)T_TOK * 4;
  int* selected = (int*)(ws + off);     off += (size_t)NQ * 4;
  int* lo = (int*)(ws + off);           off += 64;
  int* hi = (int*)(ws + off);           off += 64;
  float* topv = (float*)(ws + off);     off += (size_t)NQ * NH * KT * 4;
  int* topi = (int*)(ws + off);         off += (size_t)NQ * NH * KT * 4;
  unsigned long long* topk2 = (unsigned long long*)(ws + off);
  off += (size_t)NQ * NH * 2 * KT * 8;                                    // 0.98 MB
  (void)ws_size; (void)in_sizes; (void)n_in; (void)out_size;

  imp_kernel<<<T_TOK / 16, 128, 0, stream>>>(X, Wi1, bi1, Wi2, bi2, imp);
  topsel_kernel<<<M_MSG, 64, 0, stream>>>(imp, mb, selected);
  ranges_kernel<<<1, 8, 0, stream>>>(bidx, lo, hi);
  projkv_kernel<<<T_TOK / 16, 256, 0, stream>>>(X, Wk, bk, Wv, bv, Kmat, V);
  proj_kernel<<<NQ / 32, 256, 0, stream>>>(X, Wq, bq, Q, selected, NQ, 0.125f);
  scores_kernel<<<M_MSG * NH * 2, 128, 0, stream>>>(Q, Kmat, lo, hi, bidx,
                                                    topk2);
  merge_kernel<<<NQ * NH / 256, 256, 0, stream>>>(topk2, topv, topi);
  hipMemcpyAsync(out, X, (size_t)T_TOK * D_HID * sizeof(float),
                 hipMemcpyDeviceToDevice, stream);
  finish_kernel<<<NQ / 16, 256, 0, stream>>>(topv, topi, V, Wo, bo, selected,
                                             out, out_avg);
}

// Round 3
// 406.900 us; speedup vs baseline: 1.3710x; 1.1116x over previous
//
#include <hip/hip_runtime.h>
#include <math.h>

#define T_TOK 16384
#define M_MSG 256
#define L_TOK 64
#define KK 6
#define NQ (M_MSG * KK)   // 1536
#define D_HID 256
#define NH 4
#define HD 64
#define KT 10
#define NBATCH 8

// ---------- helpers ----------
__device__ __forceinline__ unsigned ordf(float f) {
  unsigned u = __float_as_uint(f);
  return (u & 0x80000000u) ? ~u : (u | 0x80000000u);
}
__device__ __forceinline__ float unordf(unsigned u) {
  return __uint_as_float((u & 0x80000000u) ? (u ^ 0x80000000u) : ~u);
}

// ---------- 1. importance MLP ----------
__global__ __launch_bounds__(128) void imp_kernel(
    const float* __restrict__ X, const float* __restrict__ Wi1,
    const float* __restrict__ bi1, const float* __restrict__ Wi2,
    const float* __restrict__ bi2, float* __restrict__ imp) {
  __shared__ float xs[16][256];
  __shared__ float partial[2][16];
  int t0 = blockIdx.x * 16;
  int tid = threadIdx.x;  // 0..127, = hidden index j
  const float4* Xv = (const float4*)(X + (size_t)t0 * 256);
  float4* xsv = (float4*)&xs[0][0];
  for (int r = tid; r < 1024; r += 128) xsv[r] = Xv[r];
  __syncthreads();
  float acc[16];
#pragma unroll
  for (int tt = 0; tt < 16; ++tt) acc[tt] = 0.f;
  const float4* Wrow = (const float4*)(Wi1 + tid * 256);
  for (int i4 = 0; i4 < 64; ++i4) {
    float4 w = Wrow[i4];
#pragma unroll
    for (int tt = 0; tt < 16; ++tt) {
      float4 x = ((const float4*)xs[tt])[i4];
      acc[tt] += x.x * w.x + x.y * w.y + x.z * w.z + x.w * w.w;
    }
  }
  float b1 = bi1[tid], w2 = Wi2[tid];
  float p[16];
#pragma unroll
  for (int tt = 0; tt < 16; ++tt) {
    float hh = acc[tt] + b1;
    hh = hh > 0.f ? hh : 0.f;
    p[tt] = hh * w2;
  }
#pragma unroll
  for (int s = 1; s < 64; s <<= 1) {
#pragma unroll
    for (int tt = 0; tt < 16; ++tt) p[tt] += __shfl_xor(p[tt], s, 64);
  }
  int lane = tid & 63, w = tid >> 6;
  if (lane == 0) {
#pragma unroll
    for (int tt = 0; tt < 16; ++tt) partial[w][tt] = p[tt];
  }
  __syncthreads();
  if (tid < 16) imp[t0 + tid] = partial[0][tid] + partial[1][tid] + bi2[0];
}

// ---------- 2. per-message top-6 (desc value, tie -> lower index) ----------
__global__ __launch_bounds__(64) void topsel_kernel(
    const float* __restrict__ imp, const int* __restrict__ mb,
    int* __restrict__ selected) {
  int m = blockIdx.x;
  int l = threadIdx.x;  // 0..63
  float myv = imp[m * 64 + l];
  int start = mb[2 * m];
  for (int k = 0; k < KK; ++k) {
    float rv = myv;
    int ri = l;
#pragma unroll
    for (int s = 1; s < 64; s <<= 1) {
      float ov = __shfl_xor(rv, s, 64);
      int oi = __shfl_xor(ri, s, 64);
      if (ov > rv || (ov == rv && oi < ri)) { rv = ov; ri = oi; }
    }
    if (l == 0) selected[m * KK + k] = start + ri;
    if (l == ri) myv = -INFINITY;
  }
}

// ---------- 3. batch token ranges ----------
__global__ void ranges_kernel(const int* __restrict__ bidx,
                              int* __restrict__ lo, int* __restrict__ hi) {
  int g = threadIdx.x;  // 0..7
  if (g >= NBATCH) return;
  int l = 0;
  while (l < M_MSG && bidx[l] < g) ++l;
  int h = l;
  while (h < M_MSG && bidx[h] == g) ++h;
  lo[g] = l * L_TOK;
  hi[g] = h * L_TOK;
}

// ---------- 4a. fused K+V projection ----------
// K goes to dim-major layout K4[h*16+d4][T] (float4 = dims d4*4..d4*4+3 of
// one token) via an LDS transpose; V stays row-major.
__global__ __launch_bounds__(256) void projkv_kernel(
    const float* __restrict__ X, const float* __restrict__ Wk,
    const float* __restrict__ bk, const float* __restrict__ Wv,
    const float* __restrict__ bv, float* __restrict__ Kout,
    float* __restrict__ Vout) {
  __shared__ float xs[16][260];  // +4 pad: FMA reads & transpose reads 2-way max
  int r0 = blockIdx.x * 16;
  int tid = threadIdx.x;  // output column j
  const float4* Xv = (const float4*)(X + (size_t)r0 * 256);
  for (int n = tid; n < 1024; n += 256) {
    int row = n >> 6, sl = n & 63;
    ((float4*)xs[row])[sl] = Xv[row * 64 + sl];
  }
  __syncthreads();
  float ak[16], av[16];
#pragma unroll
  for (int tt = 0; tt < 16; ++tt) { ak[tt] = 0.f; av[tt] = 0.f; }
  const float4* Wkr = (const float4*)(Wk + tid * 256);
  const float4* Wvr = (const float4*)(Wv + tid * 256);
  for (int i4 = 0; i4 < 64; ++i4) {
    float4 wk = Wkr[i4];
    float4 wv = Wvr[i4];
#pragma unroll
    for (int tt = 0; tt < 16; ++tt) {
      float4 x = ((const float4*)xs[tt])[i4];
      ak[tt] += x.x * wk.x + x.y * wk.y + x.z * wk.z + x.w * wk.w;
      av[tt] += x.x * wv.x + x.y * wv.y + x.z * wv.z + x.w * wv.w;
    }
  }
  float bkj = bk[tid], bvj = bv[tid];
  // V store (row-major, coalesced)
#pragma unroll 1
  for (int tt = 0; tt < 16; ++tt)
    Vout[(size_t)(r0 + tt) * 256 + tid] = av[tt] + bvj;
  // K transpose through LDS -> dim-major store
  __syncthreads();  // all FMA reads of xs done
#pragma unroll
  for (int tt = 0; tt < 16; ++tt) xs[tt][tid] = ak[tt] + bkj;
  __syncthreads();
  float4* K4v = (float4*)Kout;
#pragma unroll
  for (int i = 0; i < 4; ++i) {
    int idx = i * 256 + tid;
    int hd4 = idx >> 4, r = idx & 15;
    float4 kv = *(const float4*)&xs[r][hd4 * 4];
    K4v[(size_t)hd4 * T_TOK + r0 + r] = kv;
  }
}

// ---------- 4b. Q projection (row-major out, gathered rows, scaled) ----------
__global__ __launch_bounds__(256) void proj_kernel(
    const float* __restrict__ X, const float* __restrict__ W,
    const float* __restrict__ b, float* __restrict__ out,
    const int* __restrict__ rows, int R, float scale) {
  __shared__ float xs[32][256];
  int r0 = blockIdx.x * 32;
  int tid = threadIdx.x;  // output column j
  for (int rr = 0; rr < 32; ++rr) {
    int r = r0 + rr;
    if (r < R) {
      int src = rows ? rows[r] : r;
      xs[rr][tid] = X[(size_t)src * 256 + tid];
    }
  }
  __syncthreads();
  float acc[32];
#pragma unroll
  for (int tt = 0; tt < 32; ++tt) acc[tt] = 0.f;
  const float4* Wrow = (const float4*)(W + tid * 256);
  for (int i4 = 0; i4 < 64; ++i4) {
    float4 w = Wrow[i4];
#pragma unroll
    for (int tt = 0; tt < 32; ++tt) {
      float4 x = ((const float4*)xs[tt])[i4];
      acc[tt] += x.x * w.x + x.y * w.y + x.z * w.z + x.w * w.w;
    }
  }
  float bj = b[tid];
#pragma unroll 1
  for (int tt = 0; tt < 32; ++tt) {
    int r = r0 + tt;
    if (r < R) out[(size_t)r * 256 + tid] = (acc[tt] + bj) * scale;
  }
}

// ---------- 5. scores + per-split top-10 ----------
// block = (m, h, split): 2048 blocks, 128 threads = 2 waves.
// Wave w owns queries w*3+{0,1,2}; lane L owns key base+L of each 64-key
// chunk. K is dim-major K4[h*16+d4][T]: lane L's load of (d4, t=base+L) is
// 64 lanes x 16B CONTIGUOUS (1 KB/instr, perfectly coalesced) straight to
// registers -- no LDS staging of K, no barriers in the hot loop. Q is
// wave-uniform -> LDS broadcast reads (conflict-free). Both waves stream the
// same keys, so wave 1 hits L1 (chunk = 16 KB < 32 KB L1). Top-10 kept as
// per-lane register u64 lists (ord(score)<<32 | ~token); one shfl
// extraction-merge at the end.
__global__ __launch_bounds__(128) void scores_kernel(
    const float* __restrict__ Q, const float* __restrict__ K4,
    const int* __restrict__ lo_, const int* __restrict__ hi_,
    const int* __restrict__ bidx, unsigned long long* __restrict__ topk2) {
  int bid = blockIdx.x;
  // XCD swizzle: 2048 blocks, 8 XCDs -> contiguous 256-block slab per XCD
  // (bidx sorted) so each XCD's K slice stays in its L2.
  int sw = (bid & 7) * (M_MSG * NH * 2 / 8) + (bid >> 3);
  int m = sw >> 3;
  int h = (sw >> 1) & 3;
  int sp = sw & 1;
  int tid = threadIdx.x, lane = tid & 63, w = tid >> 6;
  int g = bidx[m];
  int lo = lo_[g], hi = hi_[g];
  int range = hi - lo;
  int n_all = (range + 63) >> 6;
  int n0 = (n_all + 1) >> 1;
  int nt = sp ? (n_all - n0) : n0;
  int start = lo + (sp ? n0 * 64 : 0);
  int end0 = lo + n0 * 64;
  int end = sp ? hi : (end0 < hi ? end0 : hi);

  __shared__ float4 qs4[KK][16];  // 6 queries x 64 dims (1.5 KB)
  const float4* Qv = (const float4*)Q;
  for (int i = tid; i < KK * 16; i += 128) {
    int qq = i >> 4, d4 = i & 15;
    qs4[qq][d4] = Qv[(size_t)(m * KK + qq) * 64 + h * 16 + d4];
  }
  __syncthreads();

  unsigned long long lst[3][KT];
#pragma unroll
  for (int j = 0; j < 3; ++j)
#pragma unroll
    for (int k = 0; k < KT; ++k) lst[j][k] = 0ULL;

  const float4* Kh = (const float4*)K4 + (size_t)h * 16 * T_TOK;

#pragma unroll 1
  for (int kb = 0; kb < nt; ++kb) {
    int t = start + kb * 64 + lane;
    int tc = t < hi ? t : hi - 1;
    float acc[3];
    acc[0] = 0.f; acc[1] = 0.f; acc[2] = 0.f;
#pragma unroll
    for (int half = 0; half < 2; ++half) {
      float4 ka[8];
#pragma unroll
      for (int d = 0; d < 8; ++d)
        ka[d] = Kh[(size_t)(half * 8 + d) * T_TOK + tc];
#pragma unroll
      for (int d = 0; d < 8; ++d) {
#pragma unroll
        for (int j = 0; j < 3; ++j) {
          float4 q = qs4[w * 3 + j][half * 8 + d];
          acc[j] += ka[d].x * q.x + ka[d].y * q.y + ka[d].z * q.z +
                    ka[d].w * q.w;
        }
      }
    }
    bool v0 = (t < end) && ((t >> 6) != m);
    unsigned nk = ~(unsigned)t;
#pragma unroll
    for (int j = 0; j < 3; ++j) {
      unsigned cc = v0 ? ordf(acc[j]) : 0u;
      unsigned long long key =
          cc ? (((unsigned long long)cc << 32) | nk) : 0ULL;
      if (key > lst[j][KT - 1]) {
        unsigned long long ins = key;
#pragma unroll
        for (int r = 0; r < KT; ++r) {
          unsigned long long cur = lst[j][r];
          unsigned long long mx = ins > cur ? ins : cur;
          unsigned long long mn = ins > cur ? cur : ins;
          lst[j][r] = mx;
          ins = mn;
        }
      }
    }
  }

  // ---- extraction merge across 64 lanes (3 queries interleaved for ILP) ----
  for (int k = 0; k < KT; ++k) {
    unsigned long long mx[3];
#pragma unroll
    for (int j = 0; j < 3; ++j) mx[j] = lst[j][0];
#pragma unroll
    for (int s_ = 1; s_ < 64; s_ <<= 1) {
#pragma unroll
      for (int j = 0; j < 3; ++j) {
        unsigned long long o = __shfl_xor(mx[j], s_, 64);
        if (o > mx[j]) mx[j] = o;
      }
    }
#pragma unroll
    for (int j = 0; j < 3; ++j) {
      if (mx[j] != 0ULL && lst[j][0] == mx[j]) {
#pragma unroll
        for (int r = 0; r < KT - 1; ++r) lst[j][r] = lst[j][r + 1];
        lst[j][KT - 1] = 0ULL;
      }
    }
    if (lane == 0) {
#pragma unroll
      for (int j = 0; j < 3; ++j) {
        int q = m * KK + w * 3 + j;
        topk2[((size_t)(q * NH + h) * 2 + sp) * KT + k] = mx[j];
      }
    }
  }
}

// ---------- 5b. merge the two split lists (exact, sorted) ----------
__global__ __launch_bounds__(256) void merge_kernel(
    const unsigned long long* __restrict__ topk2, float* __restrict__ topv,
    int* __restrict__ topi) {
  __shared__ unsigned long long buf[256][2 * KT];  // 40 KB
  int tid = threadIdx.x;
  int i = blockIdx.x * 256 + tid;  // (q*NH+h)
  const unsigned long long* a = topk2 + (size_t)i * 2 * KT;
#pragma unroll
  for (int k = 0; k < 2 * KT; ++k) buf[tid][k] = a[k];
  int pa = 0, pb = 0;
  float* tv = topv + (size_t)i * KT;
  int* ti = topi + (size_t)i * KT;
  for (int k = 0; k < KT; ++k) {
    unsigned long long va = buf[tid][pa];
    unsigned long long vb = buf[tid][KT + pb];
    unsigned long long v;
    if (va >= vb) { v = va; ++pa; } else { v = vb; ++pb; }
    if (v != 0ULL) {
      tv[k] = unordf((unsigned)(v >> 32));
      ti[k] = (int)(~(unsigned)v);
    } else {
      tv[k] = -1e30f;
      ti[k] = 0;
    }
  }
}

// ---------- 6. softmax + gather V + Wo matvec + scatter-add + avg_scores ----------
__global__ __launch_bounds__(256) void finish_kernel(
    const float* __restrict__ topv, const int* __restrict__ topi,
    const float* __restrict__ V, const float* __restrict__ Wo,
    const float* __restrict__ bo, const int* __restrict__ selected,
    float* __restrict__ out, float* __restrict__ out_avg) {
  int q0 = blockIdx.x * 16;
  int tid = threadIdx.x;
  __shared__ float wsm[16][NH * KT];
  __shared__ float att[16][256];
  if (tid < 64) {
    int qq = tid >> 2, h = tid & 3;
    int q = q0 + qq;
    const float* tv = topv + (size_t)(q * NH + h) * KT;
    float mx = tv[0];
    float e[KT];
    float sum = 0.f;
#pragma unroll
    for (int k = 0; k < KT; ++k) { e[k] = expf(tv[k] - mx); sum += e[k]; }
    float inv = 1.f / sum;
#pragma unroll
    for (int k = 0; k < KT; ++k) wsm[qq][h * KT + k] = e[k] * inv;
  } else if (tid < 64 + 160) {
    int i = tid - 64;
    int qq = i / 10, k = i % 10;
    int q = q0 + qq;
    out_avg[(size_t)q * KT + k] =
        0.25f * (topv[(size_t)(q * NH + 0) * KT + k] +
                 topv[(size_t)(q * NH + 1) * KT + k] +
                 topv[(size_t)(q * NH + 2) * KT + k] +
                 topv[(size_t)(q * NH + 3) * KT + k]);
  }
  __syncthreads();
  int h = tid >> 6, d = tid & 63;
#pragma unroll 1
  for (int qq = 0; qq < 16; ++qq) {
    int q = q0 + qq;
    float a = 0.f;
#pragma unroll
    for (int k = 0; k < KT; ++k) {
      int t = topi[(size_t)(q * NH + h) * KT + k];
      a += wsm[qq][h * KT + k] * V[(size_t)t * 256 + h * 64 + d];
    }
    att[qq][tid] = a;
  }
  __syncthreads();
  float acc[16];
#pragma unroll
  for (int tt = 0; tt < 16; ++tt) acc[tt] = 0.f;
  const float4* Wrow = (const float4*)(Wo + tid * 256);
  for (int i4 = 0; i4 < 64; ++i4) {
    float4 wv = Wrow[i4];
#pragma unroll
    for (int tt = 0; tt < 16; ++tt) {
      float4 x = ((const float4*)att[tt])[i4];
      acc[tt] += x.x * wv.x + x.y * wv.y + x.z * wv.z + x.w * wv.w;
    }
  }
  float bj = bo[tid];
#pragma unroll 1
  for (int tt = 0; tt < 16; ++tt) {
    int s = selected[q0 + tt];
    out[(size_t)s * 256 + tid] += acc[tt] + bj;
  }
}

// ---------- launch ----------
extern "C" void kernel_launch(void* const* d_in, const int* in_sizes, int n_in,
                              void* d_out, int out_size, void* d_ws, size_t ws_size,
                              hipStream_t stream) {
  const float* X   = (const float*)d_in[0];
  const int*   mb  = (const int*)d_in[1];
  const int*   bidx= (const int*)d_in[2];
  const float* Wq  = (const float*)d_in[3];
  const float* bq  = (const float*)d_in[4];
  const float* Wk  = (const float*)d_in[5];
  const float* bk  = (const float*)d_in[6];
  const float* Wv  = (const float*)d_in[7];
  const float* bv  = (const float*)d_in[8];
  const float* Wi1 = (const float*)d_in[9];
  const float* bi1 = (const float*)d_in[10];
  const float* Wi2 = (const float*)d_in[11];
  const float* bi2 = (const float*)d_in[12];
  const float* Wo  = (const float*)d_in[13];
  const float* bo  = (const float*)d_in[14];

  float* out = (float*)d_out;
  float* out_avg = out + (size_t)T_TOK * D_HID;

  // K is staged in d_out's "updated" region (dead until final memcpy+scatter).
  float* Kmat = out;

  char* ws = (char*)d_ws;
  size_t off = 0;
  float* V = (float*)(ws + off);        off += (size_t)T_TOK * 256 * 4;   // 16.78 MB
  float* Q = (float*)(ws + off);        off += (size_t)NQ * 256 * 4;      // 1.57 MB
  float* imp = (float*)(ws + off);      off += (size_t)T_TOK * 4;
  int* selected = (int*)(ws + off);     off += (size_t)NQ * 4;
  int* lo = (int*)(ws + off);           off += 64;
  int* hi = (int*)(ws + off);           off += 64;
  float* topv = (float*)(ws + off);     off += (size_t)NQ * NH * KT * 4;
  int* topi = (int*)(ws + off);         off += (size_t)NQ * NH * KT * 4;
  unsigned long long* topk2 = (unsigned long long*)(ws + off);
  off += (size_t)NQ * NH * 2 * KT * 8;                                    // 0.98 MB
  (void)ws_size; (void)in_sizes; (void)n_in; (void)out_size;

  imp_kernel<<<T_TOK / 16, 128, 0, stream>>>(X, Wi1, bi1, Wi2, bi2, imp);
  topsel_kernel<<<M_MSG, 64, 0, stream>>>(imp, mb, selected);
  ranges_kernel<<<1, 8, 0, stream>>>(bidx, lo, hi);
  projkv_kernel<<<T_TOK / 16, 256, 0, stream>>>(X, Wk, bk, Wv, bv, Kmat, V);
  proj_kernel<<<NQ / 32, 256, 0, stream>>>(X, Wq, bq, Q, selected, NQ, 0.125f);
  scores_kernel<<<M_MSG * NH * 2, 128, 0, stream>>>(Q, Kmat, lo, hi, bidx,
                                                    topk2);
  merge_kernel<<<NQ * NH / 256, 256, 0, stream>>>(topk2, topv, topi);
  hipMemcpyAsync(out, X, (size_t)T_TOK * D_HID * sizeof(float),
                 hipMemcpyDeviceToDevice, stream);
  finish_kernel<<<NQ / 16, 256, 0, stream>>>(topv, topi, V, Wo, bo, selected,
                                             out, out_avg);
}